// Round 12
// baseline (288.759 us; speedup 1.0000x reference)
//
#include <hip/hip_runtime.h>

#pragma clang fp contract(off)

#define NBOX 4096
#define MBOX 256
#define NBATCH 32
#define GEPS 1e-7f
#define DEPTH 12        // candidate-list depth (init)
#define RDEPTH 8        // rebuild depth (zero-padded to DEPTH)

typedef unsigned long long u64;
typedef unsigned int u32;
typedef unsigned short u16;

// ---- greedy dynamic-LDS layout (bytes) ----
#define OFF_PRS   0        // float4[4096]   65536
#define OFF_TOP   65536    // u64[256][12]   24576  ([j*12+e])
#define OFF_G     90112    // float4[256]    4096
#define OFF_GAR   94208    // f32[256]       1024
#define OFF_RL    95232    // u64[64]        512    (row-live mirror)
#define OFF_MATCH 95744    // u32[256]       1024   (packed rowfield<<9|colfield)
#define LDS_BYTES 96768

__device__ __forceinline__ u64 shflxor_u64(u64 x, int m) {
  u32 lo = (u32)x, hi = (u32)(x >> 32);
  lo = __shfl_xor(lo, m, 64);
  hi = __shfl_xor(hi, m, 64);
  return ((u64)hi << 32) | (u64)lo;
}

// 64-lane u64 max-reduce on the VALU (DPP), result uniform (readlane 63).
__device__ __forceinline__ u64 wave_max_u64(u64 x) {
  u32 lo = (u32)x, hi = (u32)(x >> 32);
#define DPPL(CTRL)                                                              \
  {                                                                             \
    u32 slo = (u32)__builtin_amdgcn_update_dpp(0, (int)lo, CTRL, 0xf, 0xf, true); \
    u32 shi = (u32)__builtin_amdgcn_update_dpp(0, (int)hi, CTRL, 0xf, 0xf, true); \
    if (((((u64)shi) << 32) | slo) > ((((u64)hi) << 32) | lo)) { lo = slo; hi = shi; } \
  }
  DPPL(0xB1)   // quad_perm xor1
  DPPL(0x4E)   // quad_perm xor2
  DPPL(0x141)  // row_half_mirror
  DPPL(0x140)  // row_mirror
  DPPL(0x142)  // row_bcast15
  DPPL(0x143)  // row_bcast31 -> lane 63 global
#undef DPPL
  lo = (u32)__builtin_amdgcn_readlane((int)lo, 63);
  hi = (u32)__builtin_amdgcn_readlane((int)hi, 63);
  return (((u64)hi) << 32) | lo;
}

// exact IEEE, contract off -> bitwise identical everywhere it's computed
__device__ __forceinline__ u32 iou_bits(float4 a, float areaA, float4 g, float gar) {
  #pragma clang fp contract(off)
  float w = fminf(a.z, g.z) - fmaxf(a.x, g.x);
  float h = fminf(a.w, g.w) - fmaxf(a.y, g.y);
  w = fmaxf(w, 0.0f);
  h = fmaxf(h, 0.0f);
  float inter = w * h;
  float uni = (areaA + gar) - inter;
  float v = inter / uni;  // IoU >= 0: float bits order-preserving
  return __float_as_uint(v);
}

__device__ __forceinline__ float giou_loss(float ax1, float ay1, float ax2, float ay2,
                                           float bx1, float by1, float bx2, float by2) {
  #pragma clang fp contract(off)
  float xi1 = fmaxf(ax1, bx1), yi1 = fmaxf(ay1, by1);
  float xi2 = fminf(ax2, bx2), yi2 = fminf(ay2, by2);
  float inter = fmaxf(xi2 - xi1, 0.0f) * fmaxf(yi2 - yi1, 0.0f);
  float area1 = (ax2 - ax1) * (ay2 - ay1);
  float area2 = (bx2 - bx1) * (by2 - by1);
  float uni = (area1 + area2) - inter;
  float iou = inter / (uni + GEPS);
  float xc1 = fminf(ax1, bx1), yc1 = fminf(ay1, by1);
  float xc2 = fmaxf(ax2, bx2), yc2 = fmaxf(ay2, by2);
  float areac = (xc2 - xc1) * (yc2 - yc1);
  float giou = iou - (areac - uni) / (areac + GEPS);
  return 1.0f - giou;
}

// col-entry key: (iou<<13)|(4096-r)               -> max == (val desc, row asc)
// global key:    (iou<<22)|((4096-r)<<9)|(256-j)  -> max == (val desc, row asc, col asc)
//                == jnp.argmax flat-index tie-break, exactly.

// one wave per col: lane-local top-12 over 64 rows, then 12x DPP wave-max extraction
__global__ __launch_bounds__(256) __attribute__((amdgpu_waves_per_eu(1, 4)))
void init_cols(const float4* __restrict__ pr, const float4* __restrict__ gt,
               u64* __restrict__ topG) {
  const int blk = blockIdx.x;
  const int b = blk >> 6, cg = blk & 63;
  const int tid = threadIdx.x, lane = tid & 63, wid = tid >> 6;
  const int j = cg * 4 + wid;
  const float4* prb = pr + (size_t)b * NBOX;
  float4 gb = gt[(size_t)b * MBOX + j];
  float gar = (gb.z - gb.x) * (gb.w - gb.y);
  u64 t[DEPTH];
  #pragma unroll
  for (int q = 0; q < DEPTH; ++q) t[q] = 0ull;
  for (int k = 0; k < 64; ++k) {
    int r = (k << 6) + lane;  // coalesced
    float4 a = prb[r];
    float areaA = (a.z - a.x) * (a.w - a.y);
    u64 key = ((u64)iou_bits(a, areaA, gb, gar) << 13) | (u64)(NBOX - r);
    if (key > t[DEPTH - 1]) {
      t[DEPTH - 1] = key;
      #pragma unroll
      for (int q = DEPTH - 1; q > 0; --q)
        if (t[q] > t[q - 1]) { u64 tmp = t[q]; t[q] = t[q - 1]; t[q - 1] = tmp; }
    }
  }
  u64* out = topG + ((size_t)b * MBOX + j) * DEPTH;
  int h = 0;
  for (int e = 0; e < DEPTH; ++e) {
    u64 cand = 0;
    #pragma unroll
    for (int q = 0; q < DEPTH; ++q) if (q == h) cand = t[q];  // static reg index
    u64 m = wave_max_u64(cand);
    if (cand == m && m) h++;  // keys distinct -> unique winner
    if (lane == 0) out[e] = m;
  }
}

// Exact sequential greedy: ONE WAVE per batch, zero barriers, DPP argmax,
// deferred loss, LIVE-LOOKAHEAD invariant: la[q] is always a currently-live
// entry (or 0 = exhausted), so cb promotion on row-death is pure register
// work; the dependent rl_lds walk runs off the critical chain as a refill.
__global__ __launch_bounds__(64) __attribute__((amdgpu_waves_per_eu(1, 4)))
void greedy_kernel(const float4* __restrict__ pr, const float4* __restrict__ gt,
                   const u64* __restrict__ topG, float* __restrict__ partial) {
  extern __shared__ char smem[];
  float4* prs  = (float4*)(smem + OFF_PRS);
  u64* top     = (u64*)(smem + OFF_TOP);    // [j*DEPTH + e]
  float4* g    = (float4*)(smem + OFF_G);
  float* garea = (float*)(smem + OFF_GAR);
  u64* rl_lds  = (u64*)(smem + OFF_RL);
  u32* match   = (u32*)(smem + OFF_MATCH);

  const int b = blockIdx.x;
  const int lane = threadIdx.x;  // 64 threads = 1 wave
  const float4* prb = pr + (size_t)b * NBOX;

  // ---- stage prs + negdiff ----
  float negdiff = 0.0f, possum = 0.0f, negsub = 0.0f;
  for (int k = 0; k < 64; ++k) {
    int r = (k << 6) + lane;
    float4 a = prb[r];
    prs[r] = a;
    negdiff += giou_loss(a.x, a.y, a.z, a.w, 0.0f, 0.0f, 0.0f, 0.0f);
  }
  // ---- stage gt ----
  #pragma unroll
  for (int k = 0; k < 4; ++k) {
    int j = (k << 6) + lane;
    float4 gg = gt[(size_t)b * MBOX + j];
    g[j] = gg;
    garea[j] = (gg.z - gg.x) * (gg.w - gg.y);
  }
  // ---- stage candidate lists (24KB, float4 copies; linear both sides) ----
  {
    float4* dst = (float4*)top;
    const float4* src = (const float4*)(topG + (size_t)b * MBOX * DEPTH);
    for (int k = 0; k < MBOX * DEPTH / 2 / 64; ++k) dst[(k << 6) + lane] = src[(k << 6) + lane];
  }
  // ---- register state ----
  u64 rowlive = ~0ull;          // bit k of lane l = row (k<<6)+l live
  rl_lds[lane] = rowlive;
  u64 cb[4];                    // colbest (global key) for col (q<<6)+lane
  u64 la[4];                    // live lookahead: next live raw entry (0 = exhausted)
  u64 cfc[4];                   // col-field constants: MBOX - j
  u32 posreg = 0x02020202u;     // 4x 8-bit next-list-index (after la)
  #pragma unroll
  for (int q = 0; q < 4; ++q) {
    int j = (q << 6) + lane;
    cfc[q] = (u64)(MBOX - j);
    u64 e0 = top[j * DEPTH];     // nonzero by construction; all rows live at init
    u64 e1 = top[j * DEPTH + 1];
    cb[q] = ((e0 >> 13) << 22) | ((e0 & 0x1FFFull) << 9) | cfc[q];
    la[q] = e1;
  }

  // ---- 256 greedy steps, zero barriers, DPP argmax, live-lookahead ----
  for (int step = 0; step < MBOX; ++step) {
    // argmax over 256 colbests: 2-level reg max + VALU DPP reduce (uniform out)
    u64 m0 = cb[0] > cb[1] ? cb[0] : cb[1];
    u64 m1 = cb[2] > cb[3] ? cb[2] : cb[3];
    u64 m = wave_max_u64(m0 > m1 ? m0 : m1);
    if (lane == 0) match[step] = (u32)m & 0x3FFFFFu;  // defer loss to tail
    if (step == MBOX - 1) break;
    const u32 rfield = (u32)(m >> 9) & 0x1FFFu;  // 4096 - i  (>= 1)
    const u32 cfield = (u32)m & 0x1FFu;          // 256 - jm  (>= 1)
    const int i = NBOX - (int)rfield;
    // row i dies: owner lane updates reg + LDS mirror (used by refills/rebuilds)
    if (lane == (i & 63)) {
      rowlive &= ~(1ull << (i >> 6));
      rl_lds[lane] = rowlive;
    }
    // slot updates: PURE REGISTER promote; walks deferred to refill block
    u32 exmask = 0, refillmask = 0;
    #pragma unroll
    for (int q = 0; q < 4; ++q) {
      u64 c = cb[q];
      u64 l = la[q];
      // cb.row and la.row are distinct rows of one col -> at most one dies/step
      const bool cbdie = (((u32)(c >> 9)) & 0x1FFFu) == rfield;  // c==0 -> 0 != rfield
      const bool ladie = ((u32)(l & 0x1FFFull)) == rfield;       // l==0 -> 0 != rfield
      if (cfield == (u32)cfc[q]) {
        cb[q] = 0ull; la[q] = 0ull;      // col matched: retire slot
        posreg |= (0xFFu << (q * 8));    // stop future refills
      } else if (cbdie) {
        if (l != 0ull) {
          cb[q] = ((l >> 13) << 22) | ((l & 0x1FFFull) << 9) | cfc[q];  // la is LIVE
          la[q] = 0ull;
          refillmask |= 1u << q;
        } else {
          cb[q] = 0ull;
          exmask |= 1u << q;             // exhausted -> rebuild
        }
      } else if (ladie) {
        la[q] = 0ull;
        refillmask |= 1u << q;
      }
    }
    // off-chain refills: find next live entry (next argmax doesn't wait on this)
    if (refillmask) {
      #pragma unroll
      for (int q = 0; q < 4; ++q) {
        if (refillmask & (1u << q)) {
          const int j = (q << 6) + lane;
          int p = (int)((posreg >> (q * 8)) & 0xFFu);
          u64 e = 0ull;
          while (p < DEPTH) {
            u64 t = top[j * DEPTH + p];
            ++p;
            if (t == 0ull) { p = DEPTH; break; }  // zero-pad from shallow rebuild
            int r = NBOX - (int)(t & 0x1FFFull);
            if ((rl_lds[r & 63] >> (r >> 6)) & 1ull) { e = t; break; }  // live
          }
          la[q] = e;  // 0 = exhausted
          posreg = (posreg & ~(0xFFu << (q * 8))) | ((u32)p << (q * 8));
        }
      }
    }
    // rare inline rebuilds (wave-uniform loop; all lanes active inside)
    u64 exb = __ballot(exmask != 0);
    while (exb != 0ull) {
      const int src = (int)__ffsll((unsigned long long)exb) - 1;
      const u32 em = (u32)__shfl((int)exmask, src, 64);
      const int q = __ffs(em) - 1;
      const int jj = (q << 6) + src;
      if (lane == src) exmask &= ~(1u << q);
      exb = __ballot(exmask != 0);
      float4 gb = g[jj];
      float gar = garea[jj];
      u64 t[RDEPTH];
      #pragma unroll
      for (int z = 0; z < RDEPTH; ++z) t[z] = 0ull;
      for (int k = 0; k < 64; ++k) {
        if ((rowlive >> k) & 1ull) {  // own-lane liveness (transposed layout)
          int rr = (k << 6) + lane;
          float4 a = prs[rr];
          float areaA = (a.z - a.x) * (a.w - a.y);
          u64 key = ((u64)iou_bits(a, areaA, gb, gar) << 13) | (u64)(NBOX - rr);
          if (key > t[RDEPTH - 1]) {
            t[RDEPTH - 1] = key;
            #pragma unroll
            for (int z = RDEPTH - 1; z > 0; --z)
              if (t[z] > t[z - 1]) { u64 tmp = t[z]; t[z] = t[z - 1]; t[z - 1] = tmp; }
          }
        }
      }
      u64 ent0 = 0ull, ent1 = 0ull;
      int h = 0;
      for (int e = 0; e < RDEPTH; ++e) {
        u64 cand = 0;
        #pragma unroll
        for (int z = 0; z < RDEPTH; ++z) if (z == h) cand = t[z];
        u64 mm = wave_max_u64(cand);
        if (cand == mm && mm) h++;
        if (e == 0) ent0 = mm;
        if (e == 1) ent1 = mm;
        if (lane == 0) top[jj * DEPTH + e] = mm;
      }
      if (lane >= RDEPTH && lane < DEPTH) top[jj * DEPTH + lane] = 0ull;  // zero-pad
      if (lane == src) {
        cb[q] = ((ent0 >> 13) << 22) | ((ent0 & 0x1FFFull) << 9) | cfc[q];
        la[q] = ent1;  // >=3840 live rows -> ent0/ent1 nonzero AND live
        posreg = (posreg & ~(0xFFu << (q * 8))) | (2u << (q * 8));
      }
    }
  }

  // ---- deferred loss: 4 matched pairs per lane ----
  #pragma unroll
  for (int t4 = 0; t4 < 4; ++t4) {
    int s = (t4 << 6) + lane;
    u32 mm = match[s];
    int i = NBOX - (int)(mm >> 9);
    int j = MBOX - (int)(mm & 0x1FFu);
    float4 a = prs[i];
    float4 gg = g[j];
    possum += giou_loss(a.x, a.y, a.z, a.w, gg.x, gg.y, gg.z, gg.w);
    negsub += giou_loss(a.x, a.y, a.z, a.w, 0.0f, 0.0f, 0.0f, 0.0f);
  }

  // ---- final wave reduce: possum/256 + (negdiff - negsub)/3840 ----
  #pragma unroll
  for (int o = 32; o; o >>= 1) {
    possum  += __shfl_xor(possum, o, 64);
    negsub  += __shfl_xor(negsub, o, 64);
    negdiff += __shfl_xor(negdiff, o, 64);
  }
  if (lane == 0)
    partial[b] = possum / 256.0f + (negdiff - negsub) / 3840.0f;
}

__global__ void finalize_kernel(const float* __restrict__ partial, float* __restrict__ out) {
  if (threadIdx.x == 0) {
    float s = 0.0f;
    for (int i = 0; i < NBATCH; ++i) s += partial[i];
    out[0] = s / 64.0f;  // /count(=32)/2
  }
}

extern "C" void kernel_launch(void* const* d_in, const int* in_sizes, int n_in,
                              void* d_out, int out_size, void* d_ws, size_t ws_size,
                              hipStream_t stream) {
  (void)in_sizes; (void)n_in; (void)out_size; (void)ws_size;
  const float4* pr = (const float4*)d_in[0];
  const float4* gt = (const float4*)d_in[1];
  char* ws = (char*)d_ws;
  u64* topG = (u64*)ws;                                    // 32*256*12*8 = 768 KB
  float* partial = (float*)(ws + (size_t)NBATCH * MBOX * DEPTH * 8);
  float* out = (float*)d_out;

  // allow >64KB dynamic LDS (idempotent host-side attribute; not a stream op)
  hipFuncSetAttribute((const void*)greedy_kernel,
                      hipFuncAttributeMaxDynamicSharedMemorySize, LDS_BYTES);

  hipLaunchKernelGGL(init_cols, dim3(NBATCH * 64), dim3(256), 0, stream, pr, gt, topG);
  hipLaunchKernelGGL(greedy_kernel, dim3(NBATCH), dim3(64), LDS_BYTES, stream,
                     pr, gt, topG, partial);
  hipLaunchKernelGGL(finalize_kernel, dim3(1), dim3(64), 0, stream, partial, out);
}

// Round 13
// 243.697 us; speedup vs baseline: 1.1849x; 1.1849x over previous
//
#include <hip/hip_runtime.h>

#pragma clang fp contract(off)

#define NBOX 4096
#define MBOX 256
#define NBATCH 32
#define GEPS 1e-7f
#define DEPTH 12        // candidate-list depth (init)
#define RDEPTH 8        // rebuild depth (zero-padded to DEPTH)

typedef unsigned long long u64;
typedef unsigned int u32;
typedef unsigned short u16;

// ---- greedy dynamic-LDS layout (bytes) ----
#define OFF_PRS   0        // float4[4096]   65536
#define OFF_TOP   65536    // u64[256][12]   24576  ([j*12+e])
#define OFF_G     90112    // float4[256]    4096
#define OFF_GAR   94208    // f32[256]       1024
#define OFF_RL    95232    // u64[64]        512    (row-live mirror)
#define OFF_MATCH 95744    // u32[256]       1024   (packed rowfield<<9|colfield)
#define LDS_BYTES 96768
#define LDS_INIT  65536    // init_cols: float4 prs[4096]

__device__ __forceinline__ u64 shflxor_u64(u64 x, int m) {
  u32 lo = (u32)x, hi = (u32)(x >> 32);
  lo = __shfl_xor(lo, m, 64);
  hi = __shfl_xor(hi, m, 64);
  return ((u64)hi << 32) | (u64)lo;
}

// 64-lane u64 max-reduce on the VALU (DPP), result uniform (readlane 63).
__device__ __forceinline__ u64 wave_max_u64(u64 x) {
  u32 lo = (u32)x, hi = (u32)(x >> 32);
#define DPPL(CTRL)                                                              \
  {                                                                             \
    u32 slo = (u32)__builtin_amdgcn_update_dpp(0, (int)lo, CTRL, 0xf, 0xf, true); \
    u32 shi = (u32)__builtin_amdgcn_update_dpp(0, (int)hi, CTRL, 0xf, 0xf, true); \
    if (((((u64)shi) << 32) | slo) > ((((u64)hi) << 32) | lo)) { lo = slo; hi = shi; } \
  }
  DPPL(0xB1)   // quad_perm xor1
  DPPL(0x4E)   // quad_perm xor2
  DPPL(0x141)  // row_half_mirror
  DPPL(0x140)  // row_mirror
  DPPL(0x142)  // row_bcast15
  DPPL(0x143)  // row_bcast31 -> lane 63 global
#undef DPPL
  lo = (u32)__builtin_amdgcn_readlane((int)lo, 63);
  hi = (u32)__builtin_amdgcn_readlane((int)hi, 63);
  return (((u64)hi) << 32) | lo;
}

// 64-lane u32 max-reduce on the VALU (DPP), result uniform (readlane 63).
__device__ __forceinline__ u32 wave_max_u32(u32 x) {
#define DPPL32(CTRL)                                                            \
  {                                                                             \
    u32 s = (u32)__builtin_amdgcn_update_dpp(0, (int)x, CTRL, 0xf, 0xf, true);  \
    x = x > s ? x : s;                                                          \
  }
  DPPL32(0xB1) DPPL32(0x4E) DPPL32(0x141) DPPL32(0x140) DPPL32(0x142) DPPL32(0x143)
#undef DPPL32
  return (u32)__builtin_amdgcn_readlane((int)x, 63);
}

// exact IEEE, contract off -> bitwise identical everywhere it's computed
__device__ __forceinline__ u32 iou_bits(float4 a, float areaA, float4 g, float gar) {
  #pragma clang fp contract(off)
  float w = fminf(a.z, g.z) - fmaxf(a.x, g.x);
  float h = fminf(a.w, g.w) - fmaxf(a.y, g.y);
  w = fmaxf(w, 0.0f);
  h = fmaxf(h, 0.0f);
  float inter = w * h;
  float uni = (areaA + gar) - inter;
  float v = inter / uni;  // IoU >= 0: float bits order-preserving
  return __float_as_uint(v);
}

__device__ __forceinline__ float giou_loss(float ax1, float ay1, float ax2, float ay2,
                                           float bx1, float by1, float bx2, float by2) {
  #pragma clang fp contract(off)
  float xi1 = fmaxf(ax1, bx1), yi1 = fmaxf(ay1, by1);
  float xi2 = fminf(ax2, bx2), yi2 = fminf(ay2, by2);
  float inter = fmaxf(xi2 - xi1, 0.0f) * fmaxf(yi2 - yi1, 0.0f);
  float area1 = (ax2 - ax1) * (ay2 - ay1);
  float area2 = (bx2 - bx1) * (by2 - by1);
  float uni = (area1 + area2) - inter;
  float iou = inter / (uni + GEPS);
  float xc1 = fminf(ax1, bx1), yc1 = fminf(ay1, by1);
  float xc2 = fmaxf(ax2, bx2), yc2 = fmaxf(ay2, by2);
  float areac = (xc2 - xc1) * (yc2 - yc1);
  float giou = iou - (areac - uni) / (areac + GEPS);
  return 1.0f - giou;
}

// col-entry key: (iou<<13)|(4096-r)               -> max == (val desc, row asc)
// global key:    (iou<<22)|((4096-r)<<9)|(256-j)  -> max == (val desc, row asc, col asc)
//                == jnp.argmax flat-index tie-break, exactly.

// LDS-staged init: 32 blocks/batch x 256 threads; block stages all 4096 pr
// boxes into LDS once (cuts L2 traffic 32x), 4 waves x 2 cols each build
// top-12 candidate lists (lane-local insertion + DPP wave-max extraction).
__global__ __launch_bounds__(256) __attribute__((amdgpu_waves_per_eu(1, 4)))
void init_cols(const float4* __restrict__ pr, const float4* __restrict__ gt,
               u64* __restrict__ topG) {
  extern __shared__ char ismem[];
  float4* prs = (float4*)ismem;
  const int blk = blockIdx.x;
  const int b = blk >> 5, s = blk & 31;   // 32 blocks per batch, 8 cols each
  const int tid = threadIdx.x, lane = tid & 63, wid = tid >> 6;
  const float4* prb = pr + (size_t)b * NBOX;
  #pragma unroll
  for (int k = 0; k < 16; ++k) {
    int r = (k << 8) + tid;
    prs[r] = prb[r];
  }
  __syncthreads();
  for (int cc = 0; cc < 2; ++cc) {
    const int j = (s << 3) + (wid << 1) + cc;
    float4 gb = gt[(size_t)b * MBOX + j];   // uniform -> broadcast
    float gar = (gb.z - gb.x) * (gb.w - gb.y);
    u64 t[DEPTH];
    #pragma unroll
    for (int q = 0; q < DEPTH; ++q) t[q] = 0ull;
    for (int k = 0; k < 64; ++k) {
      int r = (k << 6) + lane;
      float4 a = prs[r];
      float areaA = (a.z - a.x) * (a.w - a.y);
      u64 key = ((u64)iou_bits(a, areaA, gb, gar) << 13) | (u64)(NBOX - r);
      if (key > t[DEPTH - 1]) {
        t[DEPTH - 1] = key;
        #pragma unroll
        for (int q = DEPTH - 1; q > 0; --q)
          if (t[q] > t[q - 1]) { u64 tmp = t[q]; t[q] = t[q - 1]; t[q - 1] = tmp; }
      }
    }
    u64* out = topG + ((size_t)b * MBOX + j) * DEPTH;
    int h = 0;
    for (int e = 0; e < DEPTH; ++e) {
      u64 cand = 0;
      #pragma unroll
      for (int q = 0; q < DEPTH; ++q) if (q == h) cand = t[q];  // static reg index
      u64 m = wave_max_u64(cand);
      if (cand == m && m) h++;  // keys distinct -> unique winner
      if (lane == 0) out[e] = m;
    }
  }
}

// Exact sequential greedy (R11-proven structure): ONE WAVE per batch, zero
// barriers, deferred loss, raw-prefetch lookahead la[q]; NEW: 2-stage 32-bit
// DPP argmax (iou stage + tie-break stage) halves the reduce chain.
__global__ __launch_bounds__(64) __attribute__((amdgpu_waves_per_eu(1, 4)))
void greedy_kernel(const float4* __restrict__ pr, const float4* __restrict__ gt,
                   const u64* __restrict__ topG, float* __restrict__ partial) {
  extern __shared__ char smem[];
  float4* prs  = (float4*)(smem + OFF_PRS);
  u64* top     = (u64*)(smem + OFF_TOP);    // [j*DEPTH + e]
  float4* g    = (float4*)(smem + OFF_G);
  float* garea = (float*)(smem + OFF_GAR);
  u64* rl_lds  = (u64*)(smem + OFF_RL);
  u32* match   = (u32*)(smem + OFF_MATCH);

  const int b = blockIdx.x;
  const int lane = threadIdx.x;  // 64 threads = 1 wave
  const float4* prb = pr + (size_t)b * NBOX;

  // ---- stage prs + negdiff ----
  float negdiff = 0.0f, possum = 0.0f, negsub = 0.0f;
  for (int k = 0; k < 64; ++k) {
    int r = (k << 6) + lane;
    float4 a = prb[r];
    prs[r] = a;
    negdiff += giou_loss(a.x, a.y, a.z, a.w, 0.0f, 0.0f, 0.0f, 0.0f);
  }
  // ---- stage gt ----
  #pragma unroll
  for (int k = 0; k < 4; ++k) {
    int j = (k << 6) + lane;
    float4 gg = gt[(size_t)b * MBOX + j];
    g[j] = gg;
    garea[j] = (gg.z - gg.x) * (gg.w - gg.y);
  }
  // ---- stage candidate lists (24KB, float4 copies; linear both sides) ----
  {
    float4* dst = (float4*)top;
    const float4* src = (const float4*)(topG + (size_t)b * MBOX * DEPTH);
    for (int k = 0; k < MBOX * DEPTH / 2 / 64; ++k) dst[(k << 6) + lane] = src[(k << 6) + lane];
  }
  // ---- register state ----
  u64 rowlive = ~0ull;          // bit k of lane l = row (k<<6)+l live
  rl_lds[lane] = rowlive;
  u64 cb[4];                    // colbest (global key) for col (q<<6)+lane
  u64 la[4];                    // lookahead: next raw list entry (0 = exhausted)
  u64 cfc[4];                   // col-field constants: MBOX - j
  u32 posreg = 0x02020202u;     // 4x 8-bit next-list-index (after la)
  #pragma unroll
  for (int q = 0; q < 4; ++q) {
    int j = (q << 6) + lane;
    cfc[q] = (u64)(MBOX - j);
    u64 e0 = top[j * DEPTH];     // nonzero by construction
    u64 e1 = top[j * DEPTH + 1];
    cb[q] = ((e0 >> 13) << 22) | ((e0 & 0x1FFFull) << 9) | cfc[q];
    la[q] = e1;
  }

  // ---- 256 greedy steps, zero barriers, 2-stage DPP argmax, deferred loss ----
  for (int step = 0; step < MBOX; ++step) {
    // per-lane max over 4 slots (u64 lexicographic == (iou, row, col) order)
    u64 m0 = cb[0] > cb[1] ? cb[0] : cb[1];
    u64 m1 = cb[2] > cb[3] ? cb[2] : cb[3];
    u64 mb = m0 > m1 ? m0 : m1;
    // stage 1: max iou (key>>22 = iou_bits, < 2^30)
    u32 iou32 = (u32)(mb >> 22);
    u32 maxiou = wave_max_u32(iou32);
    // stage 2: among lanes at max iou, max tie-break (rowfield<<9|colfield).
    // Retired slots (mb==0) have tb==0 < any valid tb (colfield >= 1).
    u32 tb = (iou32 == maxiou) ? ((u32)mb & 0x3FFFFFu) : 0u;
    u32 maxtb = wave_max_u32(tb);
    if (lane == 0) match[step] = maxtb;  // defer loss to tail
    if (step == MBOX - 1) break;
    const u32 rfield = (maxtb >> 9) & 0x1FFFu;  // 4096 - i  (>= 1)
    const u32 cfield = maxtb & 0x1FFu;          // 256 - jm  (>= 1)
    const int i = NBOX - (int)rfield;
    // row i dies: owner lane updates reg + LDS mirror (same-wave DS order)
    if (lane == (i & 63)) {
      rowlive &= ~(1ull << (i >> 6));
      rl_lds[lane] = rowlive;
    }
    // slot updates: lookahead-first walk (R11-proven)
    u32 exmask = 0;
    #pragma unroll
    for (int q = 0; q < 4; ++q) {
      const int j = (q << 6) + lane;
      u64 c = cb[q];
      if (cfield == (u32)cfc[q]) {
        cb[q] = 0ull;  // matched col retires
      } else if (((u32)(c >> 9) & 0x1FFFu) == rfield) {  // c==0 -> rowfield 0 != rfield
        int p = (int)((posreg >> (q * 8)) & 0xFFu);
        u64 e = la[q];  // pre-loaded candidate: one dependent rl read on the chain
        for (;;) {
          if (e == 0ull) break;  // exhausted (or zero-pad)
          int r = NBOX - (int)(e & 0x1FFFull);
          if ((rl_lds[r & 63] >> (r >> 6)) & 1ull) break;  // live
          e = (p < DEPTH) ? top[j * DEPTH + p] : 0ull;
          ++p;
        }
        if (e != 0ull) {
          cb[q] = ((e >> 13) << 22) | ((e & 0x1FFFull) << 9) | cfc[q];
          la[q] = (p < DEPTH) ? top[j * DEPTH + p] : 0ull;  // refill: latency hides
          ++p;
          posreg = (posreg & ~(0xFFu << (q * 8))) | ((u32)p << (q * 8));
        } else {
          cb[q] = 0ull;
          exmask |= (1u << q);
        }
      }
    }
    // rare inline rebuilds (wave-uniform loop; all lanes active inside)
    u64 exb = __ballot(exmask != 0);
    while (exb != 0ull) {
      const int src = (int)__ffsll((unsigned long long)exb) - 1;
      const u32 em = (u32)__shfl((int)exmask, src, 64);
      const int q = __ffs(em) - 1;
      const int jj = (q << 6) + src;
      if (lane == src) exmask &= ~(1u << q);
      exb = __ballot(exmask != 0);
      float4 gb = g[jj];
      float gar = garea[jj];
      u64 t[RDEPTH];
      #pragma unroll
      for (int z = 0; z < RDEPTH; ++z) t[z] = 0ull;
      for (int k = 0; k < 64; ++k) {
        if ((rowlive >> k) & 1ull) {  // own-lane liveness (transposed layout)
          int rr = (k << 6) + lane;
          float4 a = prs[rr];
          float areaA = (a.z - a.x) * (a.w - a.y);
          u64 key = ((u64)iou_bits(a, areaA, gb, gar) << 13) | (u64)(NBOX - rr);
          if (key > t[RDEPTH - 1]) {
            t[RDEPTH - 1] = key;
            #pragma unroll
            for (int z = RDEPTH - 1; z > 0; --z)
              if (t[z] > t[z - 1]) { u64 tmp = t[z]; t[z] = t[z - 1]; t[z - 1] = tmp; }
          }
        }
      }
      u64 ent0 = 0ull, ent1 = 0ull;
      int h = 0;
      for (int e = 0; e < RDEPTH; ++e) {
        u64 cand = 0;
        #pragma unroll
        for (int z = 0; z < RDEPTH; ++z) if (z == h) cand = t[z];
        u64 mm = wave_max_u64(cand);
        if (cand == mm && mm) h++;
        if (e == 0) ent0 = mm;
        if (e == 1) ent1 = mm;
        if (lane == 0) top[jj * DEPTH + e] = mm;
      }
      if (lane >= RDEPTH && lane < DEPTH) top[jj * DEPTH + lane] = 0ull;  // zero-pad
      if (lane == src) {
        cb[q] = ((ent0 >> 13) << 22) | ((ent0 & 0x1FFFull) << 9) | cfc[q];
        la[q] = ent1;  // >=3840 live rows -> ent0/ent1 nonzero, live
        posreg = (posreg & ~(0xFFu << (q * 8))) | (2u << (q * 8));
      }
    }
  }

  // ---- deferred loss: 4 matched pairs per lane ----
  #pragma unroll
  for (int t4 = 0; t4 < 4; ++t4) {
    int s = (t4 << 6) + lane;
    u32 mm = match[s];
    int i = NBOX - (int)(mm >> 9);
    int j = MBOX - (int)(mm & 0x1FFu);
    float4 a = prs[i];
    float4 gg = g[j];
    possum += giou_loss(a.x, a.y, a.z, a.w, gg.x, gg.y, gg.z, gg.w);
    negsub += giou_loss(a.x, a.y, a.z, a.w, 0.0f, 0.0f, 0.0f, 0.0f);
  }

  // ---- final wave reduce: possum/256 + (negdiff - negsub)/3840 ----
  #pragma unroll
  for (int o = 32; o; o >>= 1) {
    possum  += __shfl_xor(possum, o, 64);
    negsub  += __shfl_xor(negsub, o, 64);
    negdiff += __shfl_xor(negdiff, o, 64);
  }
  if (lane == 0)
    partial[b] = possum / 256.0f + (negdiff - negsub) / 3840.0f;
}

__global__ void finalize_kernel(const float* __restrict__ partial, float* __restrict__ out) {
  if (threadIdx.x == 0) {
    float s = 0.0f;
    for (int i = 0; i < NBATCH; ++i) s += partial[i];
    out[0] = s / 64.0f;  // /count(=32)/2
  }
}

extern "C" void kernel_launch(void* const* d_in, const int* in_sizes, int n_in,
                              void* d_out, int out_size, void* d_ws, size_t ws_size,
                              hipStream_t stream) {
  (void)in_sizes; (void)n_in; (void)out_size; (void)ws_size;
  const float4* pr = (const float4*)d_in[0];
  const float4* gt = (const float4*)d_in[1];
  char* ws = (char*)d_ws;
  u64* topG = (u64*)ws;                                    // 32*256*12*8 = 768 KB
  float* partial = (float*)(ws + (size_t)NBATCH * MBOX * DEPTH * 8);
  float* out = (float*)d_out;

  // allow large dynamic LDS (idempotent host-side attributes; not stream ops)
  hipFuncSetAttribute((const void*)greedy_kernel,
                      hipFuncAttributeMaxDynamicSharedMemorySize, LDS_BYTES);
  hipFuncSetAttribute((const void*)init_cols,
                      hipFuncAttributeMaxDynamicSharedMemorySize, LDS_INIT);

  hipLaunchKernelGGL(init_cols, dim3(NBATCH * 32), dim3(256), LDS_INIT, stream,
                     pr, gt, topG);
  hipLaunchKernelGGL(greedy_kernel, dim3(NBATCH), dim3(64), LDS_BYTES, stream,
                     pr, gt, topG, partial);
  hipLaunchKernelGGL(finalize_kernel, dim3(1), dim3(64), 0, stream, partial, out);
}

// Round 14
// 183.131 us; speedup vs baseline: 1.5768x; 1.3307x over previous
//
#include <hip/hip_runtime.h>

#pragma clang fp contract(off)

#define NBOX 4096
#define MBOX 256
#define NBATCH 32
#define GEPS 1e-7f
#define DEPTH 12        // candidate-list depth (init)
#define RDEPTH 8        // rebuild depth (zero-padded to DEPTH)

typedef unsigned long long u64;
typedef unsigned int u32;
typedef unsigned short u16;

// ---- greedy dynamic-LDS layout (bytes) ----
#define OFF_PRS   0        // float4[4096]   65536
#define OFF_TOP   65536    // u64[256][12]   24576  ([j*12+e])
#define OFF_G     90112    // float4[256]    4096
#define OFF_GAR   94208    // f32[256]       1024
#define OFF_RL    95232    // u64[64]        512    (row-live mirror, lazily updated)
#define OFF_MATCH 95744    // u32[256]       1024   (packed rowfield<<9|colfield)
#define LDS_BYTES 96768

// 64-lane u32 max-reduce on the VALU (DPP), result uniform (readlane 63).
__device__ __forceinline__ u32 wave_max_u32(u32 x) {
#define DPPL32(CTRL)                                                            \
  {                                                                             \
    u32 s = (u32)__builtin_amdgcn_update_dpp(0, (int)x, CTRL, 0xf, 0xf, true);  \
    x = x > s ? x : s;                                                          \
  }
  DPPL32(0xB1) DPPL32(0x4E) DPPL32(0x141) DPPL32(0x140) DPPL32(0x142) DPPL32(0x143)
#undef DPPL32
  return (u32)__builtin_amdgcn_readlane((int)x, 63);
}

// 2-stage max for col-entry keys (iou<<13 | (4096-r)): stage1 iou, stage2 rowfield.
// Exactly reproduces u64 max (iou desc, row asc); result uniform.
__device__ __forceinline__ u64 wave_max_colkey(u64 key) {
  u32 iou = (u32)(key >> 13);
  u32 maxiou = wave_max_u32(iou);
  u32 tb = (iou == maxiou) ? ((u32)key & 0x1FFFu) : 0u;  // empty (key=0) -> tb 0
  u32 maxtb = wave_max_u32(tb);
  return ((u64)maxiou << 13) | (u64)maxtb;
}

// exact IEEE, contract off -> bitwise identical everywhere it's computed
__device__ __forceinline__ u32 iou_bits(float4 a, float areaA, float4 g, float gar) {
  #pragma clang fp contract(off)
  float w = fminf(a.z, g.z) - fmaxf(a.x, g.x);
  float h = fminf(a.w, g.w) - fmaxf(a.y, g.y);
  w = fmaxf(w, 0.0f);
  h = fmaxf(h, 0.0f);
  float inter = w * h;
  float uni = (areaA + gar) - inter;
  float v = inter / uni;  // IoU >= 0: float bits order-preserving
  return __float_as_uint(v);
}

__device__ __forceinline__ float giou_loss(float ax1, float ay1, float ax2, float ay2,
                                           float bx1, float by1, float bx2, float by2) {
  #pragma clang fp contract(off)
  float xi1 = fmaxf(ax1, bx1), yi1 = fmaxf(ay1, by1);
  float xi2 = fminf(ax2, bx2), yi2 = fminf(ay2, by2);
  float inter = fmaxf(xi2 - xi1, 0.0f) * fmaxf(yi2 - yi1, 0.0f);
  float area1 = (ax2 - ax1) * (ay2 - ay1);
  float area2 = (bx2 - bx1) * (by2 - by1);
  float uni = (area1 + area2) - inter;
  float iou = inter / (uni + GEPS);
  float xc1 = fminf(ax1, bx1), yc1 = fminf(ay1, by1);
  float xc2 = fmaxf(ax2, bx2), yc2 = fmaxf(ay2, by2);
  float areac = (xc2 - xc1) * (yc2 - yc1);
  float giou = iou - (areac - uni) / (areac + GEPS);
  return 1.0f - giou;
}

// col-entry key: (iou<<13)|(4096-r)               -> max == (val desc, row asc)
// global key:    (iou<<22)|((4096-r)<<9)|(256-j)  -> max == (val desc, row asc, col asc)
//                == jnp.argmax flat-index tie-break, exactly.

// one wave per col (R11-proven structure): lane-local top-12 over 64 rows,
// then 12x 2-stage DPP extraction (halved vs u64 wave-max).
__global__ __launch_bounds__(256) __attribute__((amdgpu_waves_per_eu(1, 6)))
void init_cols(const float4* __restrict__ pr, const float4* __restrict__ gt,
               u64* __restrict__ topG) {
  const int blk = blockIdx.x;
  const int b = blk >> 6, cg = blk & 63;
  const int tid = threadIdx.x, lane = tid & 63, wid = tid >> 6;
  const int j = cg * 4 + wid;
  const float4* prb = pr + (size_t)b * NBOX;
  float4 gb = gt[(size_t)b * MBOX + j];
  float gar = (gb.z - gb.x) * (gb.w - gb.y);
  u64 t[DEPTH];
  #pragma unroll
  for (int q = 0; q < DEPTH; ++q) t[q] = 0ull;
  for (int k = 0; k < 64; ++k) {
    int r = (k << 6) + lane;  // coalesced
    float4 a = prb[r];
    float areaA = (a.z - a.x) * (a.w - a.y);
    u64 key = ((u64)iou_bits(a, areaA, gb, gar) << 13) | (u64)(NBOX - r);
    if (key > t[DEPTH - 1]) {
      t[DEPTH - 1] = key;
      #pragma unroll
      for (int q = DEPTH - 1; q > 0; --q)
        if (t[q] > t[q - 1]) { u64 tmp = t[q]; t[q] = t[q - 1]; t[q - 1] = tmp; }
    }
  }
  u64* out = topG + ((size_t)b * MBOX + j) * DEPTH;
  int h = 0;
  for (int e = 0; e < DEPTH; ++e) {
    u64 cand = 0;
    #pragma unroll
    for (int q = 0; q < DEPTH; ++q) if (q == h) cand = t[q];  // static reg index
    u64 m = wave_max_colkey(cand);
    if (cand == m && m) h++;  // keys distinct -> unique winner
    if (lane == 0) out[e] = m;
  }
}

// Exact sequential greedy: ONE WAVE per batch, zero barriers, 2-stage DPP
// argmax, deferred loss. NEW: zero-LDS common path — rowlive update is
// branchless register-only; the rl_lds mirror is written LAZILY, only on
// steps where some slot must walk (written immediately before the walk
// reads it; same-wave DS order makes it current; rebuilds use registers).
__global__ __launch_bounds__(64) __attribute__((amdgpu_waves_per_eu(1, 4)))
void greedy_kernel(const float4* __restrict__ pr, const float4* __restrict__ gt,
                   const u64* __restrict__ topG, float* __restrict__ partial) {
  extern __shared__ char smem[];
  float4* prs  = (float4*)(smem + OFF_PRS);
  u64* top     = (u64*)(smem + OFF_TOP);    // [j*DEPTH + e]
  float4* g    = (float4*)(smem + OFF_G);
  float* garea = (float*)(smem + OFF_GAR);
  u64* rl_lds  = (u64*)(smem + OFF_RL);
  u32* match   = (u32*)(smem + OFF_MATCH);

  const int b = blockIdx.x;
  const int lane = threadIdx.x;  // 64 threads = 1 wave
  const float4* prb = pr + (size_t)b * NBOX;

  // ---- stage prs + negdiff ----
  float negdiff = 0.0f, possum = 0.0f, negsub = 0.0f;
  for (int k = 0; k < 64; ++k) {
    int r = (k << 6) + lane;
    float4 a = prb[r];
    prs[r] = a;
    negdiff += giou_loss(a.x, a.y, a.z, a.w, 0.0f, 0.0f, 0.0f, 0.0f);
  }
  // ---- stage gt ----
  #pragma unroll
  for (int k = 0; k < 4; ++k) {
    int j = (k << 6) + lane;
    float4 gg = gt[(size_t)b * MBOX + j];
    g[j] = gg;
    garea[j] = (gg.z - gg.x) * (gg.w - gg.y);
  }
  // ---- stage candidate lists (24KB, float4 copies; linear both sides) ----
  {
    float4* dst = (float4*)top;
    const float4* src = (const float4*)(topG + (size_t)b * MBOX * DEPTH);
    for (int k = 0; k < MBOX * DEPTH / 2 / 64; ++k) dst[(k << 6) + lane] = src[(k << 6) + lane];
  }
  // ---- register state ----
  u64 rowlive = ~0ull;          // bit k of lane l = row (k<<6)+l live
  u64 cb[4];                    // colbest (global key) for col (q<<6)+lane
  u64 la[4];                    // lookahead: next raw list entry (0 = exhausted)
  u64 cfc[4];                   // col-field constants: MBOX - j
  u32 posreg = 0x02020202u;     // 4x 8-bit next-list-index (after la)
  #pragma unroll
  for (int q = 0; q < 4; ++q) {
    int j = (q << 6) + lane;
    cfc[q] = (u64)(MBOX - j);
    u64 e0 = top[j * DEPTH];     // nonzero by construction
    u64 e1 = top[j * DEPTH + 1];
    cb[q] = ((e0 >> 13) << 22) | ((e0 & 0x1FFFull) << 9) | cfc[q];
    la[q] = e1;
  }

  // ---- 256 greedy steps ----
  for (int step = 0; step < MBOX; ++step) {
    // per-lane max over 4 slots, then 2-stage DPP argmax (uniform result)
    u64 m0 = cb[0] > cb[1] ? cb[0] : cb[1];
    u64 m1 = cb[2] > cb[3] ? cb[2] : cb[3];
    u64 mb = m0 > m1 ? m0 : m1;
    u32 iou32 = (u32)(mb >> 22);
    u32 maxiou = wave_max_u32(iou32);
    u32 tb = (iou32 == maxiou) ? ((u32)mb & 0x3FFFFFu) : 0u;  // retired: tb 0
    u32 maxtb = wave_max_u32(tb);
    if (lane == 0) match[step] = maxtb;  // defer loss to tail
    if (step == MBOX - 1) break;
    const u32 rfield = (maxtb >> 9) & 0x1FFFu;  // 4096 - i  (>= 1)
    const int i = NBOX - (int)rfield;
    // row i dies: branchless register update (all lanes)
    u64 kill = (lane == (i & 63)) ? (1ull << (i >> 6)) : 0ull;
    rowlive &= ~kill;
    // branchless slot checks: affected = rowfield match; matched col = full low22
    u32 walkmask = 0;
    #pragma unroll
    for (int q = 0; q < 4; ++q) {
      u32 lo22 = (u32)cb[q] & 0x3FFFFFu;
      bool aff = (lo22 >> 9) == rfield;        // cb==0 -> 0 != rfield
      bool ismatch = (lo22 == maxtb);
      if (aff && ismatch) cb[q] = 0ull;        // matched col retires
      if (aff && !ismatch) walkmask |= (1u << q);
    }
    u64 wb = __ballot(walkmask != 0);
    if (wb != 0ull) {  // rare path: someone's cb died -> mirror + walks
      rl_lds[lane] = rowlive;  // make mirror current (DS order before reads)
      u32 exmask = 0;
      #pragma unroll
      for (int q = 0; q < 4; ++q) {
        if (walkmask & (1u << q)) {
          const int j = (q << 6) + lane;
          int p = (int)((posreg >> (q * 8)) & 0xFFu);
          u64 e = la[q];
          for (;;) {
            if (e == 0ull) break;  // exhausted (or zero-pad)
            int r = NBOX - (int)(e & 0x1FFFull);
            if ((rl_lds[r & 63] >> (r >> 6)) & 1ull) break;  // live
            e = (p < DEPTH) ? top[j * DEPTH + p] : 0ull;
            ++p;
          }
          if (e != 0ull) {
            cb[q] = ((e >> 13) << 22) | ((e & 0x1FFFull) << 9) | cfc[q];
            la[q] = (p < DEPTH) ? top[j * DEPTH + p] : 0ull;  // refill off-chain
            ++p;
            posreg = (posreg & ~(0xFFu << (q * 8))) | ((u32)p << (q * 8));
          } else {
            cb[q] = 0ull;
            exmask |= (1u << q);
          }
        }
      }
      // rare inline rebuilds (wave-uniform loop; all lanes active inside)
      u64 exb = __ballot(exmask != 0);
      while (exb != 0ull) {
        const int src = (int)__ffsll((unsigned long long)exb) - 1;
        const u32 em = (u32)__shfl((int)exmask, src, 64);
        const int q = __ffs(em) - 1;
        const int jj = (q << 6) + src;
        if (lane == src) exmask &= ~(1u << q);
        exb = __ballot(exmask != 0);
        float4 gb = g[jj];
        float gar = garea[jj];
        u64 t[RDEPTH];
        #pragma unroll
        for (int z = 0; z < RDEPTH; ++z) t[z] = 0ull;
        for (int k = 0; k < 64; ++k) {
          if ((rowlive >> k) & 1ull) {  // own-lane liveness (transposed layout)
            int rr = (k << 6) + lane;
            float4 a = prs[rr];
            float areaA = (a.z - a.x) * (a.w - a.y);
            u64 key = ((u64)iou_bits(a, areaA, gb, gar) << 13) | (u64)(NBOX - rr);
            if (key > t[RDEPTH - 1]) {
              t[RDEPTH - 1] = key;
              #pragma unroll
              for (int z = RDEPTH - 1; z > 0; --z)
                if (t[z] > t[z - 1]) { u64 tmp = t[z]; t[z] = t[z - 1]; t[z - 1] = tmp; }
            }
          }
        }
        u64 ent0 = 0ull, ent1 = 0ull;
        int h = 0;
        for (int e = 0; e < RDEPTH; ++e) {
          u64 cand = 0;
          #pragma unroll
          for (int z = 0; z < RDEPTH; ++z) if (z == h) cand = t[z];
          u64 mm = wave_max_colkey(cand);
          if (cand == mm && mm) h++;
          if (e == 0) ent0 = mm;
          if (e == 1) ent1 = mm;
          if (lane == 0) top[jj * DEPTH + e] = mm;
        }
        if (lane >= RDEPTH && lane < DEPTH) top[jj * DEPTH + lane] = 0ull;  // zero-pad
        if (lane == src) {
          cb[q] = ((ent0 >> 13) << 22) | ((ent0 & 0x1FFFull) << 9) | cfc[q];
          la[q] = ent1;  // >=3840 live rows -> ent0/ent1 nonzero, live
          posreg = (posreg & ~(0xFFu << (q * 8))) | (2u << (q * 8));
        }
      }
    }
  }

  // ---- deferred loss: 4 matched pairs per lane ----
  #pragma unroll
  for (int t4 = 0; t4 < 4; ++t4) {
    int s = (t4 << 6) + lane;
    u32 mm = match[s];
    int i = NBOX - (int)(mm >> 9);
    int j = MBOX - (int)(mm & 0x1FFu);
    float4 a = prs[i];
    float4 gg = g[j];
    possum += giou_loss(a.x, a.y, a.z, a.w, gg.x, gg.y, gg.z, gg.w);
    negsub += giou_loss(a.x, a.y, a.z, a.w, 0.0f, 0.0f, 0.0f, 0.0f);
  }

  // ---- final wave reduce: possum/256 + (negdiff - negsub)/3840 ----
  #pragma unroll
  for (int o = 32; o; o >>= 1) {
    possum  += __shfl_xor(possum, o, 64);
    negsub  += __shfl_xor(negsub, o, 64);
    negdiff += __shfl_xor(negdiff, o, 64);
  }
  if (lane == 0)
    partial[b] = possum / 256.0f + (negdiff - negsub) / 3840.0f;
}

__global__ void finalize_kernel(const float* __restrict__ partial, float* __restrict__ out) {
  if (threadIdx.x == 0) {
    float s = 0.0f;
    for (int i = 0; i < NBATCH; ++i) s += partial[i];
    out[0] = s / 64.0f;  // /count(=32)/2
  }
}

extern "C" void kernel_launch(void* const* d_in, const int* in_sizes, int n_in,
                              void* d_out, int out_size, void* d_ws, size_t ws_size,
                              hipStream_t stream) {
  (void)in_sizes; (void)n_in; (void)out_size; (void)ws_size;
  const float4* pr = (const float4*)d_in[0];
  const float4* gt = (const float4*)d_in[1];
  char* ws = (char*)d_ws;
  u64* topG = (u64*)ws;                                    // 32*256*12*8 = 768 KB
  float* partial = (float*)(ws + (size_t)NBATCH * MBOX * DEPTH * 8);
  float* out = (float*)d_out;

  // allow >64KB dynamic LDS (idempotent host-side attribute; not a stream op)
  hipFuncSetAttribute((const void*)greedy_kernel,
                      hipFuncAttributeMaxDynamicSharedMemorySize, LDS_BYTES);

  hipLaunchKernelGGL(init_cols, dim3(NBATCH * 64), dim3(256), 0, stream, pr, gt, topG);
  hipLaunchKernelGGL(greedy_kernel, dim3(NBATCH), dim3(64), LDS_BYTES, stream,
                     pr, gt, topG, partial);
  hipLaunchKernelGGL(finalize_kernel, dim3(1), dim3(64), 0, stream, partial, out);
}

// Round 15
// 166.265 us; speedup vs baseline: 1.7367x; 1.1014x over previous
//
#include <hip/hip_runtime.h>

#pragma clang fp contract(off)

#define NBOX 4096
#define MBOX 256
#define NBATCH 32
#define GEPS 1e-7f
#define DEPTH 12        // candidate-list depth (init)
#define RDEPTH 8        // rebuild depth (zero-padded to DEPTH)

typedef unsigned long long u64;
typedef unsigned int u32;
typedef unsigned short u16;

// ---- greedy dynamic-LDS layout (bytes) ----
#define OFF_PRS   0        // float4[4096]   65536
#define OFF_TOP   65536    // u64[256][12]   24576  ([j*12+e])
#define OFF_G     90112    // float4[256]    4096
#define OFF_GAR   94208    // f32[256]       1024
#define OFF_RL    95232    // u64[64]        512    (row-live mirror, lazily updated)
#define OFF_MATCH 95744    // u32[256]       1024   (packed rowfield<<9|colfield)
#define LDS_BYTES 96768

// 64-lane u32 max-reduce on the VALU (DPP), result uniform (readlane 63).
__device__ __forceinline__ u32 wave_max_u32(u32 x) {
#define DPPL32(CTRL)                                                            \
  {                                                                             \
    u32 s = (u32)__builtin_amdgcn_update_dpp(0, (int)x, CTRL, 0xf, 0xf, true);  \
    x = x > s ? x : s;                                                          \
  }
  DPPL32(0xB1) DPPL32(0x4E) DPPL32(0x141) DPPL32(0x140) DPPL32(0x142) DPPL32(0x143)
#undef DPPL32
  return (u32)__builtin_amdgcn_readlane((int)x, 63);
}

// 2-stage max for col-entry keys (iou<<13 | (4096-r)): stage1 iou, stage2 rowfield.
// Exactly reproduces u64 max (iou desc, row asc); result uniform.
__device__ __forceinline__ u64 wave_max_colkey(u64 key) {
  u32 iou = (u32)(key >> 13);
  u32 maxiou = wave_max_u32(iou);
  u32 tb = (iou == maxiou) ? ((u32)key & 0x1FFFu) : 0u;  // empty (key=0) -> tb 0
  u32 maxtb = wave_max_u32(tb);
  return ((u64)maxiou << 13) | (u64)maxtb;
}

// exact IEEE, contract off -> bitwise identical everywhere it's computed
__device__ __forceinline__ u32 iou_bits(float4 a, float areaA, float4 g, float gar) {
  #pragma clang fp contract(off)
  float w = fminf(a.z, g.z) - fmaxf(a.x, g.x);
  float h = fminf(a.w, g.w) - fmaxf(a.y, g.y);
  w = fmaxf(w, 0.0f);
  h = fmaxf(h, 0.0f);
  float inter = w * h;
  float uni = (areaA + gar) - inter;
  float v = inter / uni;  // IoU >= 0: float bits order-preserving
  return __float_as_uint(v);
}

__device__ __forceinline__ float giou_loss(float ax1, float ay1, float ax2, float ay2,
                                           float bx1, float by1, float bx2, float by2) {
  #pragma clang fp contract(off)
  float xi1 = fmaxf(ax1, bx1), yi1 = fmaxf(ay1, by1);
  float xi2 = fminf(ax2, bx2), yi2 = fminf(ay2, by2);
  float inter = fmaxf(xi2 - xi1, 0.0f) * fmaxf(yi2 - yi1, 0.0f);
  float area1 = (ax2 - ax1) * (ay2 - ay1);
  float area2 = (bx2 - bx1) * (by2 - by1);
  float uni = (area1 + area2) - inter;
  float iou = inter / (uni + GEPS);
  float xc1 = fminf(ax1, bx1), yc1 = fminf(ay1, by1);
  float xc2 = fmaxf(ax2, bx2), yc2 = fmaxf(ay2, by2);
  float areac = (xc2 - xc1) * (yc2 - yc1);
  float giou = iou - (areac - uni) / (areac + GEPS);
  return 1.0f - giou;
}

// col-entry key: (iou<<13)|(4096-r)               -> max == (val desc, row asc)
// global key:    (iou<<22)|((4096-r)<<9)|(256-j)  -> max == (val desc, row asc, col asc)
//                == jnp.argmax flat-index tie-break, exactly.

// one wave per col. NEW (R15): depth-3 per-lane scan with exact max-discarded
// tracking (dm). Global top-12 of the union of lane top-3s is exact unless
// some lane discarded a key > the extracted 12th (dm > m12) -> rare exact
// fallback (full depth-12 rescan of that column). E[top-12 per lane]=0.1875,
// so P(fallback) ~ 3e-3 per column (~24 columns total).
__global__ __launch_bounds__(256) __attribute__((amdgpu_waves_per_eu(1, 6)))
void init_cols(const float4* __restrict__ pr, const float4* __restrict__ gt,
               u64* __restrict__ topG) {
  const int blk = blockIdx.x;
  const int b = blk >> 6, cg = blk & 63;
  const int tid = threadIdx.x, lane = tid & 63, wid = tid >> 6;
  const int j = cg * 4 + wid;
  const float4* prb = pr + (size_t)b * NBOX;
  float4 gb = gt[(size_t)b * MBOX + j];
  float gar = (gb.z - gb.x) * (gb.w - gb.y);

  // depth-3 per-lane top (independent-update form) + exact discard max
  u64 t0 = 0ull, t1 = 0ull, t2 = 0ull, dm = 0ull;
  for (int k = 0; k < 64; ++k) {
    int r = (k << 6) + lane;  // coalesced
    float4 a = prb[r];
    float areaA = (a.z - a.x) * (a.w - a.y);
    u64 key = ((u64)iou_bits(a, areaA, gb, gar) << 13) | (u64)(NBOX - r);
    bool c0 = key > t0, c1 = key > t1, c2 = key > t2;
    u64 d = c2 ? t2 : key;            // discarded this iter = min(key, t2)
    if (d > dm) dm = d;
    u64 n1 = c1 ? (c0 ? t0 : key) : t1;
    u64 n2 = c2 ? (c1 ? t1 : key) : t2;
    t0 = c0 ? key : t0;
    t1 = n1;
    t2 = n2;
  }
  u64* out = topG + ((size_t)b * MBOX + j) * DEPTH;
  int h = 0;
  u64 m12 = 0ull;
  for (int e = 0; e < DEPTH; ++e) {
    u64 cand = (h == 0) ? t0 : (h == 1) ? t1 : (h == 2) ? t2 : 0ull;
    u64 m = wave_max_colkey(cand);
    if (cand == m && m) h++;  // keys distinct -> unique winner
    if (lane == 0) out[e] = m;
    m12 = m;
  }
  // exact fallback: some lane discarded a key that could be in the top-12
  if (__ballot(dm > m12) != 0ull) {
    u64 t[DEPTH];
    #pragma unroll
    for (int q = 0; q < DEPTH; ++q) t[q] = 0ull;
    for (int k = 0; k < 64; ++k) {
      int r = (k << 6) + lane;
      float4 a = prb[r];
      float areaA = (a.z - a.x) * (a.w - a.y);
      u64 key = ((u64)iou_bits(a, areaA, gb, gar) << 13) | (u64)(NBOX - r);
      if (key > t[DEPTH - 1]) {
        t[DEPTH - 1] = key;
        #pragma unroll
        for (int q = DEPTH - 1; q > 0; --q)
          if (t[q] > t[q - 1]) { u64 tmp = t[q]; t[q] = t[q - 1]; t[q - 1] = tmp; }
      }
    }
    int h2 = 0;
    for (int e = 0; e < DEPTH; ++e) {
      u64 cand = 0;
      #pragma unroll
      for (int q = 0; q < DEPTH; ++q) if (q == h2) cand = t[q];  // static reg index
      u64 m = wave_max_colkey(cand);
      if (cand == m && m) h2++;
      if (lane == 0) out[e] = m;
    }
  }
}

// Exact sequential greedy (R14-proven, unchanged): ONE WAVE per batch, zero
// barriers, 2-stage DPP argmax, deferred loss, zero-LDS common path with
// lazy rl_lds mirror.
__global__ __launch_bounds__(64) __attribute__((amdgpu_waves_per_eu(1, 4)))
void greedy_kernel(const float4* __restrict__ pr, const float4* __restrict__ gt,
                   const u64* __restrict__ topG, float* __restrict__ partial) {
  extern __shared__ char smem[];
  float4* prs  = (float4*)(smem + OFF_PRS);
  u64* top     = (u64*)(smem + OFF_TOP);    // [j*DEPTH + e]
  float4* g    = (float4*)(smem + OFF_G);
  float* garea = (float*)(smem + OFF_GAR);
  u64* rl_lds  = (u64*)(smem + OFF_RL);
  u32* match   = (u32*)(smem + OFF_MATCH);

  const int b = blockIdx.x;
  const int lane = threadIdx.x;  // 64 threads = 1 wave
  const float4* prb = pr + (size_t)b * NBOX;

  // ---- stage prs + negdiff ----
  float negdiff = 0.0f, possum = 0.0f, negsub = 0.0f;
  for (int k = 0; k < 64; ++k) {
    int r = (k << 6) + lane;
    float4 a = prb[r];
    prs[r] = a;
    negdiff += giou_loss(a.x, a.y, a.z, a.w, 0.0f, 0.0f, 0.0f, 0.0f);
  }
  // ---- stage gt ----
  #pragma unroll
  for (int k = 0; k < 4; ++k) {
    int j = (k << 6) + lane;
    float4 gg = gt[(size_t)b * MBOX + j];
    g[j] = gg;
    garea[j] = (gg.z - gg.x) * (gg.w - gg.y);
  }
  // ---- stage candidate lists (24KB, float4 copies; linear both sides) ----
  {
    float4* dst = (float4*)top;
    const float4* src = (const float4*)(topG + (size_t)b * MBOX * DEPTH);
    for (int k = 0; k < MBOX * DEPTH / 2 / 64; ++k) dst[(k << 6) + lane] = src[(k << 6) + lane];
  }
  // ---- register state ----
  u64 rowlive = ~0ull;          // bit k of lane l = row (k<<6)+l live
  u64 cb[4];                    // colbest (global key) for col (q<<6)+lane
  u64 la[4];                    // lookahead: next raw list entry (0 = exhausted)
  u64 cfc[4];                   // col-field constants: MBOX - j
  u32 posreg = 0x02020202u;     // 4x 8-bit next-list-index (after la)
  #pragma unroll
  for (int q = 0; q < 4; ++q) {
    int j = (q << 6) + lane;
    cfc[q] = (u64)(MBOX - j);
    u64 e0 = top[j * DEPTH];     // nonzero by construction
    u64 e1 = top[j * DEPTH + 1];
    cb[q] = ((e0 >> 13) << 22) | ((e0 & 0x1FFFull) << 9) | cfc[q];
    la[q] = e1;
  }

  // ---- 256 greedy steps ----
  for (int step = 0; step < MBOX; ++step) {
    // per-lane max over 4 slots, then 2-stage DPP argmax (uniform result)
    u64 m0 = cb[0] > cb[1] ? cb[0] : cb[1];
    u64 m1 = cb[2] > cb[3] ? cb[2] : cb[3];
    u64 mb = m0 > m1 ? m0 : m1;
    u32 iou32 = (u32)(mb >> 22);
    u32 maxiou = wave_max_u32(iou32);
    u32 tb = (iou32 == maxiou) ? ((u32)mb & 0x3FFFFFu) : 0u;  // retired: tb 0
    u32 maxtb = wave_max_u32(tb);
    if (lane == 0) match[step] = maxtb;  // defer loss to tail
    if (step == MBOX - 1) break;
    const u32 rfield = (maxtb >> 9) & 0x1FFFu;  // 4096 - i  (>= 1)
    const int i = NBOX - (int)rfield;
    // row i dies: branchless register update (all lanes)
    u64 kill = (lane == (i & 63)) ? (1ull << (i >> 6)) : 0ull;
    rowlive &= ~kill;
    // branchless slot checks: affected = rowfield match; matched col = full low22
    u32 walkmask = 0;
    #pragma unroll
    for (int q = 0; q < 4; ++q) {
      u32 lo22 = (u32)cb[q] & 0x3FFFFFu;
      bool aff = (lo22 >> 9) == rfield;        // cb==0 -> 0 != rfield
      bool ismatch = (lo22 == maxtb);
      if (aff && ismatch) cb[q] = 0ull;        // matched col retires
      if (aff && !ismatch) walkmask |= (1u << q);
    }
    u64 wb = __ballot(walkmask != 0);
    if (wb != 0ull) {  // rare path: someone's cb died -> mirror + walks
      rl_lds[lane] = rowlive;  // make mirror current (DS order before reads)
      u32 exmask = 0;
      #pragma unroll
      for (int q = 0; q < 4; ++q) {
        if (walkmask & (1u << q)) {
          const int j = (q << 6) + lane;
          int p = (int)((posreg >> (q * 8)) & 0xFFu);
          u64 e = la[q];
          for (;;) {
            if (e == 0ull) break;  // exhausted (or zero-pad)
            int r = NBOX - (int)(e & 0x1FFFull);
            if ((rl_lds[r & 63] >> (r >> 6)) & 1ull) break;  // live
            e = (p < DEPTH) ? top[j * DEPTH + p] : 0ull;
            ++p;
          }
          if (e != 0ull) {
            cb[q] = ((e >> 13) << 22) | ((e & 0x1FFFull) << 9) | cfc[q];
            la[q] = (p < DEPTH) ? top[j * DEPTH + p] : 0ull;  // refill off-chain
            ++p;
            posreg = (posreg & ~(0xFFu << (q * 8))) | ((u32)p << (q * 8));
          } else {
            cb[q] = 0ull;
            exmask |= (1u << q);
          }
        }
      }
      // rare inline rebuilds (wave-uniform loop; all lanes active inside)
      u64 exb = __ballot(exmask != 0);
      while (exb != 0ull) {
        const int src = (int)__ffsll((unsigned long long)exb) - 1;
        const u32 em = (u32)__shfl((int)exmask, src, 64);
        const int q = __ffs(em) - 1;
        const int jj = (q << 6) + src;
        if (lane == src) exmask &= ~(1u << q);
        exb = __ballot(exmask != 0);
        float4 gb = g[jj];
        float gar = garea[jj];
        u64 t[RDEPTH];
        #pragma unroll
        for (int z = 0; z < RDEPTH; ++z) t[z] = 0ull;
        for (int k = 0; k < 64; ++k) {
          if ((rowlive >> k) & 1ull) {  // own-lane liveness (transposed layout)
            int rr = (k << 6) + lane;
            float4 a = prs[rr];
            float areaA = (a.z - a.x) * (a.w - a.y);
            u64 key = ((u64)iou_bits(a, areaA, gb, gar) << 13) | (u64)(NBOX - rr);
            if (key > t[RDEPTH - 1]) {
              t[RDEPTH - 1] = key;
              #pragma unroll
              for (int z = RDEPTH - 1; z > 0; --z)
                if (t[z] > t[z - 1]) { u64 tmp = t[z]; t[z] = t[z - 1]; t[z - 1] = tmp; }
            }
          }
        }
        u64 ent0 = 0ull, ent1 = 0ull;
        int h = 0;
        for (int e = 0; e < RDEPTH; ++e) {
          u64 cand = 0;
          #pragma unroll
          for (int z = 0; z < RDEPTH; ++z) if (z == h) cand = t[z];
          u64 mm = wave_max_colkey(cand);
          if (cand == mm && mm) h++;
          if (e == 0) ent0 = mm;
          if (e == 1) ent1 = mm;
          if (lane == 0) top[jj * DEPTH + e] = mm;
        }
        if (lane >= RDEPTH && lane < DEPTH) top[jj * DEPTH + lane] = 0ull;  // zero-pad
        if (lane == src) {
          cb[q] = ((ent0 >> 13) << 22) | ((ent0 & 0x1FFFull) << 9) | cfc[q];
          la[q] = ent1;  // >=3840 live rows -> ent0/ent1 nonzero, live
          posreg = (posreg & ~(0xFFu << (q * 8))) | (2u << (q * 8));
        }
      }
    }
  }

  // ---- deferred loss: 4 matched pairs per lane ----
  #pragma unroll
  for (int t4 = 0; t4 < 4; ++t4) {
    int s = (t4 << 6) + lane;
    u32 mm = match[s];
    int i = NBOX - (int)(mm >> 9);
    int j = MBOX - (int)(mm & 0x1FFu);
    float4 a = prs[i];
    float4 gg = g[j];
    possum += giou_loss(a.x, a.y, a.z, a.w, gg.x, gg.y, gg.z, gg.w);
    negsub += giou_loss(a.x, a.y, a.z, a.w, 0.0f, 0.0f, 0.0f, 0.0f);
  }

  // ---- final wave reduce: possum/256 + (negdiff - negsub)/3840 ----
  #pragma unroll
  for (int o = 32; o; o >>= 1) {
    possum  += __shfl_xor(possum, o, 64);
    negsub  += __shfl_xor(negsub, o, 64);
    negdiff += __shfl_xor(negdiff, o, 64);
  }
  if (lane == 0)
    partial[b] = possum / 256.0f + (negdiff - negsub) / 3840.0f;
}

__global__ void finalize_kernel(const float* __restrict__ partial, float* __restrict__ out) {
  if (threadIdx.x == 0) {
    float s = 0.0f;
    for (int i = 0; i < NBATCH; ++i) s += partial[i];
    out[0] = s / 64.0f;  // /count(=32)/2
  }
}

extern "C" void kernel_launch(void* const* d_in, const int* in_sizes, int n_in,
                              void* d_out, int out_size, void* d_ws, size_t ws_size,
                              hipStream_t stream) {
  (void)in_sizes; (void)n_in; (void)out_size; (void)ws_size;
  const float4* pr = (const float4*)d_in[0];
  const float4* gt = (const float4*)d_in[1];
  char* ws = (char*)d_ws;
  u64* topG = (u64*)ws;                                    // 32*256*12*8 = 768 KB
  float* partial = (float*)(ws + (size_t)NBATCH * MBOX * DEPTH * 8);
  float* out = (float*)d_out;

  // allow >64KB dynamic LDS (idempotent host-side attribute; not a stream op)
  hipFuncSetAttribute((const void*)greedy_kernel,
                      hipFuncAttributeMaxDynamicSharedMemorySize, LDS_BYTES);

  hipLaunchKernelGGL(init_cols, dim3(NBATCH * 64), dim3(256), 0, stream, pr, gt, topG);
  hipLaunchKernelGGL(greedy_kernel, dim3(NBATCH), dim3(64), LDS_BYTES, stream,
                     pr, gt, topG, partial);
  hipLaunchKernelGGL(finalize_kernel, dim3(1), dim3(64), 0, stream, partial, out);
}